// Round 3
// baseline (196.036 us; speedup 1.0000x reference)
//
#include <hip/hip_runtime.h>

// MechanisticNRTLLoss — B=1e6 samples, scalar fp32 loss.
// R3: LDS-staged coalesced loads. All global traffic is float4-coalesced:
//   Stage A: pred -> LDS (sup MSE fused inline with target, which never hits LDS),
//            g -> LDS.  Consume: xE/xR, tau/G mats, lgE/lgR, phy.
//   Stage B: dirs + noise -> LDS. Consume: Gibbs-Duhem + TPD.
// Per-block partials -> tiny reduce kernel.

constexpr float ALPHA    = 0.3f;
constexpr float R_GAS    = 8.314462618f;
constexpr float EPS      = 1e-12f;
constexpr float TAU_CLIP = 10.0f;
constexpr float LN_CLIP  = 20.0f;
constexpr float EPS_FD   = 1e-4f;

constexpr float LOG2E = 1.44269504088896340736f;
constexpr float LN2   = 0.69314718055994530942f;

__device__ __forceinline__ float clipf(float v, float lo, float hi) {
    return fminf(fmaxf(v, lo), hi);
}
__device__ __forceinline__ float fast_rcp(float x) { return __builtin_amdgcn_rcpf(x); }

struct Mats {
    float tau[3][3];
    float G[3][3];
    float tG[3][3];
};

__device__ __forceinline__ void ln_gamma3(const float x[3], const Mats& M, float lg[3]) {
    float ratio[3], invd[3];
#pragma unroll
    for (int i = 0; i < 3; ++i) {
        float d = x[0] * M.G[0][i] + x[1] * M.G[1][i] + x[2] * M.G[2][i];
        d = fmaxf(d, EPS);
        float A = x[0] * M.tG[0][i] + x[1] * M.tG[1][i] + x[2] * M.tG[2][i];
        float inv = fast_rcp(d);
        invd[i] = inv;
        ratio[i] = A * inv;
    }
#pragma unroll
    for (int i = 0; i < 3; ++i) {
        float s = ratio[i];
#pragma unroll
        for (int j = 0; j < 3; ++j) {
            s += x[j] * M.G[i][j] * invd[j] * (M.tau[i][j] - ratio[j]);
        }
        lg[i] = clipf(s, -LN_CLIP, LN_CLIP);
    }
}

__device__ __forceinline__ void renorm3(float x[3]) {
    x[0] = fmaxf(x[0], 0.0f);
    x[1] = fmaxf(x[1], 0.0f);
    x[2] = fmaxf(x[2], 0.0f);
    float inv = fast_rcp(fmaxf(x[0] + x[1] + x[2], EPS));
    x[0] *= inv; x[1] *= inv; x[2] *= inv;
}

__global__ __launch_bounds__(256) void nrtl_loss_kernel(
    const float* __restrict__ pred,   // (B,6)
    const float* __restrict__ target, // (B,6)
    const float* __restrict__ Tarr,   // (B,)
    const float* __restrict__ g,      // (B,3,3)
    const float* __restrict__ dirs,   // (2,B,3)
    const float* __restrict__ noise,  // (4,B,3)
    float* __restrict__ partials, int B)
{
    // Stage A: pred [0,1536) + g [1536,3840). Stage B: dirs [0,1536) + noise [1536,4608).
    __shared__ __align__(16) float s[4608];

    const int t  = threadIdx.x;
    const int s0 = blockIdx.x * 256;
    const int ns = min(256, B - s0);
    const int i  = s0 + t;
    const bool valid = (t < ns);

    const float invB  = 1.0f / (float)B;
    const float SUP_W = invB * (1.0f / 6.0f);
    const float PHY_W = invB * (1.0f / 3.0f);          // LAM_PHY=1
    const float GD_W  = invB * 0.1f * 0.5f;            // LAM_GD / N_DIR
    const float TPD_W = invB * 0.1f * 0.25f;           // LAM_TPD / N_TRIAL

    float contrib = 0.0f;

    // ---- Stage A: coalesced float4 loads ----
    {
        const int npf = ns * 6;
        const int npf4 = npf >> 2;
        const float4* pg = (const float4*)(pred   + (size_t)s0 * 6);
        const float4* tg = (const float4*)(target + (size_t)s0 * 6);
        float4* sp = (float4*)s;
        for (int j = t; j < npf4; j += 256) {
            float4 pv = pg[j];
            float4 tv = tg[j];
            float dx = pv.x - tv.x, dy = pv.y - tv.y, dz = pv.z - tv.z, dw = pv.w - tv.w;
            contrib += SUP_W * (dx * dx + dy * dy + dz * dz + dw * dw);
            sp[j] = pv;
        }
        for (int j = (npf4 << 2) + t; j < npf; j += 256) {  // robustness tail
            float pv = pred[(size_t)s0 * 6 + j];
            float tv = target[(size_t)s0 * 6 + j];
            float d = pv - tv;
            contrib += SUP_W * d * d;
            s[j] = pv;
        }
        const int ngf = ns * 9;
        const int ngf4 = ngf >> 2;
        const float4* gg = (const float4*)(g + (size_t)s0 * 9);
        float4* sg = (float4*)(s + 1536);
        for (int j = t; j < ngf4; j += 256) sg[j] = gg[j];
        for (int j = (ngf4 << 2) + t; j < ngf; j += 256) s[1536 + j] = g[(size_t)s0 * 9 + j];
    }
    __syncthreads();

    float xE[3], lgE[3], logxE[3];
    Mats M;
    if (valid) {
        float p6[6];
#pragma unroll
        for (int k = 0; k < 6; ++k) p6[k] = s[t * 6 + k];
        float xR[3] = {p6[3], p6[4], p6[5]};
        xE[0] = p6[0]; xE[1] = p6[1]; xE[2] = p6[2];
        renorm3(xE);
        renorm3(xR);

        const float Tc = fmaxf(Tarr[i], 1.0f);
        const float invRT = fast_rcp(R_GAS * Tc);
#pragma unroll
        for (int a = 0; a < 3; ++a) {
#pragma unroll
            for (int b = 0; b < 3; ++b) {
                float ta = clipf(s[1536 + t * 9 + a * 3 + b] * invRT, -TAU_CLIP, TAU_CLIP);
                float Gv = __builtin_amdgcn_exp2f((-ALPHA * LOG2E) * ta);
                M.tau[a][b] = ta;
                M.G[a][b]   = Gv;
                M.tG[a][b]  = ta * Gv;
            }
        }

        float lgR[3];
        ln_gamma3(xE, M, lgE);
        ln_gamma3(xR, M, lgR);

        float phy = 0.0f;
#pragma unroll
        for (int k = 0; k < 3; ++k) {
            logxE[k] = LN2 * __builtin_amdgcn_logf(fmaxf(xE[k], EPS));
            float logxR = LN2 * __builtin_amdgcn_logf(fmaxf(xR[k], EPS));
            float r = logxE[k] + lgE[k] - logxR - lgR[k];
            phy += r * r;
        }
        contrib += PHY_W * phy;
    }
    __syncthreads();  // stage A consume done; LDS free for stage B

    // ---- Stage B: dirs (2 slabs) + noise (4 slabs), coalesced float4 ----
    {
#pragma unroll
        for (int d = 0; d < 2; ++d) {
            const int nf = ns * 3, nf4 = nf >> 2;
            const float* gsrc = dirs + ((size_t)d * B + s0) * 3;
            const float4* g4 = (const float4*)gsrc;
            float4* d4 = (float4*)(s + d * 768);
            for (int j = t; j < nf4; j += 256) d4[j] = g4[j];
            for (int j = (nf4 << 2) + t; j < nf; j += 256) s[d * 768 + j] = gsrc[j];
        }
#pragma unroll
        for (int tr = 0; tr < 4; ++tr) {
            const int nf = ns * 3, nf4 = nf >> 2;
            const float* gsrc = noise + ((size_t)tr * B + s0) * 3;
            const float4* g4 = (const float4*)gsrc;
            float4* d4 = (float4*)(s + 1536 + tr * 768);
            for (int j = t; j < nf4; j += 256) d4[j] = g4[j];
            for (int j = (nf4 << 2) + t; j < nf; j += 256) s[1536 + tr * 768 + j] = gsrc[j];
        }
    }
    __syncthreads();

    if (valid) {
        // Gibbs-Duhem
        float gdsum = 0.0f;
#pragma unroll
        for (int d = 0; d < 2; ++d) {
            float dv[3];
#pragma unroll
            for (int k = 0; k < 3; ++k) dv[k] = s[d * 768 + t * 3 + k];
            float xp[3], xm[3];
#pragma unroll
            for (int k = 0; k < 3; ++k) {
                xp[k] = xE[k] + EPS_FD * dv[k];
                xm[k] = xE[k] - EPS_FD * dv[k];
            }
            renorm3(xp);
            renorm3(xm);
            float lgp[3], lgm[3];
            ln_gamma3(xp, M, lgp);
            ln_gamma3(xm, M, lgm);
            float gd = 0.0f;
            const float inv2e = 0.5f / EPS_FD;
#pragma unroll
            for (int k = 0; k < 3; ++k) gd += xE[k] * ((lgp[k] - lgm[k]) * inv2e);
            gdsum += gd * gd;
        }
        contrib += GD_W * gdsum;

        // TPD
        float tpdsum = 0.0f;
#pragma unroll
        for (int tr = 0; tr < 4; ++tr) {
            float w[3];
#pragma unroll
            for (int k = 0; k < 3; ++k) w[k] = xE[k] + s[1536 + tr * 768 + t * 3 + k];
            renorm3(w);
            float lgw[3];
            ln_gamma3(w, M, lgw);
            float tpd = 0.0f;
#pragma unroll
            for (int k = 0; k < 3; ++k) {
                float logw = LN2 * __builtin_amdgcn_logf(fmaxf(w[k], EPS));
                tpd += w[k] * (logw + lgw[k] - logxE[k] - lgE[k]);
            }
            tpdsum += fmaxf(-tpd, 0.0f);  // MARGIN = 0
        }
        contrib += TPD_W * tpdsum;
    }

    // ---- block reduction ----
#pragma unroll
    for (int off = 32; off > 0; off >>= 1)
        contrib += __shfl_down(contrib, off, 64);

    __shared__ float ssum[4];
    const int lane = threadIdx.x & 63;
    const int wid  = threadIdx.x >> 6;
    if (lane == 0) ssum[wid] = contrib;
    __syncthreads();
    if (threadIdx.x == 0) {
        partials[blockIdx.x] = ssum[0] + ssum[1] + ssum[2] + ssum[3];
    }
}

__global__ __launch_bounds__(256) void reduce_kernel(
    const float* __restrict__ partials, int n, float* __restrict__ out)
{
    double sacc = 0.0;
    for (int j = threadIdx.x; j < n; j += 256) sacc += (double)partials[j];
#pragma unroll
    for (int off = 32; off > 0; off >>= 1)
        sacc += __shfl_down(sacc, off, 64);
    __shared__ double ds[4];
    const int lane = threadIdx.x & 63;
    const int wid  = threadIdx.x >> 6;
    if (lane == 0) ds[wid] = sacc;
    __syncthreads();
    if (threadIdx.x == 0) out[0] = (float)(ds[0] + ds[1] + ds[2] + ds[3]);
}

extern "C" void kernel_launch(void* const* d_in, const int* in_sizes, int n_in,
                              void* d_out, int out_size, void* d_ws, size_t ws_size,
                              hipStream_t stream) {
    const float* pred   = (const float*)d_in[0];
    const float* target = (const float*)d_in[1];
    const float* Tarr   = (const float*)d_in[2];
    const float* g      = (const float*)d_in[3];
    const float* dirs   = (const float*)d_in[4];
    const float* noise  = (const float*)d_in[5];
    const int B = in_sizes[2];  // T is (B,)

    float* partials = (float*)d_ws;
    float* out      = (float*)d_out;

    const int block = 256;
    const int grid  = (B + block - 1) / block;
    nrtl_loss_kernel<<<grid, block, 0, stream>>>(pred, target, Tarr, g, dirs, noise, partials, B);
    reduce_kernel<<<1, block, 0, stream>>>(partials, grid, out);
}

// Round 4
// 181.459 us; speedup vs baseline: 1.0803x; 1.0803x over previous
//
#include <hip/hip_runtime.h>

// MechanisticNRTLLoss — B=1e6 samples, scalar fp32 loss.
// R4: R2 structure + ALL global loads hoisted to registers up front (~30
// independent VMEM ops -> one waitcnt covers all: MLP instead of serial
// dependent gathers). Math identical to R2 (fast rcp/exp2/log2).
// Per-block partials -> tiny reduce kernel.

constexpr float ALPHA    = 0.3f;
constexpr float R_GAS    = 8.314462618f;
constexpr float EPS      = 1e-12f;
constexpr float TAU_CLIP = 10.0f;
constexpr float LN_CLIP  = 20.0f;
constexpr float EPS_FD   = 1e-4f;

constexpr float LOG2E = 1.44269504088896340736f;
constexpr float LN2   = 0.69314718055994530942f;

__device__ __forceinline__ float clipf(float v, float lo, float hi) {
    return fminf(fmaxf(v, lo), hi);
}
__device__ __forceinline__ float fast_rcp(float x) { return __builtin_amdgcn_rcpf(x); }

struct Mats {
    float tau[3][3];
    float G[3][3];
    float tG[3][3];
};

__device__ __forceinline__ void ln_gamma3(const float x[3], const Mats& M, float lg[3]) {
    float ratio[3], invd[3];
#pragma unroll
    for (int i = 0; i < 3; ++i) {
        float d = x[0] * M.G[0][i] + x[1] * M.G[1][i] + x[2] * M.G[2][i];
        d = fmaxf(d, EPS);
        float A = x[0] * M.tG[0][i] + x[1] * M.tG[1][i] + x[2] * M.tG[2][i];
        float inv = fast_rcp(d);
        invd[i] = inv;
        ratio[i] = A * inv;
    }
#pragma unroll
    for (int i = 0; i < 3; ++i) {
        float s = ratio[i];
#pragma unroll
        for (int j = 0; j < 3; ++j) {
            s += x[j] * M.G[i][j] * invd[j] * (M.tau[i][j] - ratio[j]);
        }
        lg[i] = clipf(s, -LN_CLIP, LN_CLIP);
    }
}

__device__ __forceinline__ void renorm3(float x[3]) {
    x[0] = fmaxf(x[0], 0.0f);
    x[1] = fmaxf(x[1], 0.0f);
    x[2] = fmaxf(x[2], 0.0f);
    float inv = fast_rcp(fmaxf(x[0] + x[1] + x[2], EPS));
    x[0] *= inv; x[1] *= inv; x[2] *= inv;
}

__global__ __launch_bounds__(256) void nrtl_loss_kernel(
    const float* __restrict__ pred,   // (B,6)
    const float* __restrict__ target, // (B,6)
    const float* __restrict__ Tarr,   // (B,)
    const float* __restrict__ g,      // (B,3,3)
    const float* __restrict__ dirs,   // (2,B,3)
    const float* __restrict__ noise,  // (4,B,3)
    float* __restrict__ partials, int B)
{
    const int i = blockIdx.x * blockDim.x + threadIdx.x;
    float contrib = 0.0f;

    if (i < B) {
        // ================= batched loads: all independent, issued first ====
        const float* prow = pred   + (size_t)i * 6;   // rows 8B-aligned
        const float* trow = target + (size_t)i * 6;
        const float* grow = g      + (size_t)i * 9;   // rows only 4B-aligned
        float2 p01 = *(const float2*)(prow);
        float2 p23 = *(const float2*)(prow + 2);
        float2 p45 = *(const float2*)(prow + 4);
        float2 t01 = *(const float2*)(trow);
        float2 t23 = *(const float2*)(trow + 2);
        float2 t45 = *(const float2*)(trow + 4);
        float Tv = Tarr[i];
        float gv[9];
#pragma unroll
        for (int k = 0; k < 9; ++k) gv[k] = grow[k];
        float dv[2][3];
#pragma unroll
        for (int d = 0; d < 2; ++d) {
            const float* drow = dirs + ((size_t)d * B + i) * 3;
#pragma unroll
            for (int k = 0; k < 3; ++k) dv[d][k] = drow[k];
        }
        float nv[4][3];
#pragma unroll
        for (int tr = 0; tr < 4; ++tr) {
            const float* nrow = noise + ((size_t)tr * B + i) * 3;
#pragma unroll
            for (int k = 0; k < 3; ++k) nv[tr][k] = nrow[k];
        }
        // ================= compute =========================================
        float sup;
        {
            float d0 = p01.x - t01.x, d1 = p01.y - t01.y;
            float d2 = p23.x - t23.x, d3 = p23.y - t23.y;
            float d4 = p45.x - t45.x, d5 = p45.y - t45.y;
            sup = d0 * d0 + d1 * d1 + d2 * d2 + d3 * d3 + d4 * d4 + d5 * d5;
        }

        float xE[3] = {p01.x, p01.y, p23.x};
        float xR[3] = {p23.y, p45.x, p45.y};
        renorm3(xE);
        renorm3(xR);

        const float Tc = fmaxf(Tv, 1.0f);
        const float invRT = fast_rcp(R_GAS * Tc);
        Mats M;
#pragma unroll
        for (int a = 0; a < 3; ++a) {
#pragma unroll
            for (int b = 0; b < 3; ++b) {
                float ta = clipf(gv[a * 3 + b] * invRT, -TAU_CLIP, TAU_CLIP);
                float Gv = __builtin_amdgcn_exp2f((-ALPHA * LOG2E) * ta);
                M.tau[a][b] = ta;
                M.G[a][b]   = Gv;
                M.tG[a][b]  = ta * Gv;
            }
        }

        float lgE[3], lgR[3];
        ln_gamma3(xE, M, lgE);
        ln_gamma3(xR, M, lgR);

        float logxE[3];
        float phy = 0.0f;
#pragma unroll
        for (int k = 0; k < 3; ++k) {
            logxE[k] = LN2 * __builtin_amdgcn_logf(fmaxf(xE[k], EPS));
            float logxR = LN2 * __builtin_amdgcn_logf(fmaxf(xR[k], EPS));
            float r = logxE[k] + lgE[k] - logxR - lgR[k];
            phy += r * r;
        }

        float gdsum = 0.0f;
#pragma unroll
        for (int d = 0; d < 2; ++d) {
            float xp[3], xm[3];
#pragma unroll
            for (int k = 0; k < 3; ++k) {
                xp[k] = xE[k] + EPS_FD * dv[d][k];
                xm[k] = xE[k] - EPS_FD * dv[d][k];
            }
            renorm3(xp);
            renorm3(xm);
            float lgp[3], lgm[3];
            ln_gamma3(xp, M, lgp);
            ln_gamma3(xm, M, lgm);
            float gd = 0.0f;
            const float inv2e = 0.5f / EPS_FD;
#pragma unroll
            for (int k = 0; k < 3; ++k) gd += xE[k] * ((lgp[k] - lgm[k]) * inv2e);
            gdsum += gd * gd;
        }

        float tpdsum = 0.0f;
#pragma unroll
        for (int tr = 0; tr < 4; ++tr) {
            float w[3];
#pragma unroll
            for (int k = 0; k < 3; ++k) w[k] = xE[k] + nv[tr][k];
            renorm3(w);
            float lgw[3];
            ln_gamma3(w, M, lgw);
            float tpd = 0.0f;
#pragma unroll
            for (int k = 0; k < 3; ++k) {
                float logw = LN2 * __builtin_amdgcn_logf(fmaxf(w[k], EPS));
                tpd += w[k] * (logw + lgw[k] - logxE[k] - lgE[k]);
            }
            tpdsum += fmaxf(-tpd, 0.0f);  // MARGIN = 0
        }

        const float invB = 1.0f / (float)B;
        contrib = invB * (sup * (1.0f / 6.0f)
                          + phy * (1.0f / 3.0f)
                          + 0.1f * gdsum * 0.5f
                          + 0.1f * tpdsum * 0.25f);
    }

    // ---- block reduction: wave shuffle then LDS across 4 waves ----
#pragma unroll
    for (int off = 32; off > 0; off >>= 1)
        contrib += __shfl_down(contrib, off, 64);

    __shared__ float ssum[4];
    const int lane = threadIdx.x & 63;
    const int wid  = threadIdx.x >> 6;
    if (lane == 0) ssum[wid] = contrib;
    __syncthreads();
    if (threadIdx.x == 0) {
        partials[blockIdx.x] = ssum[0] + ssum[1] + ssum[2] + ssum[3];
    }
}

__global__ __launch_bounds__(256) void reduce_kernel(
    const float* __restrict__ partials, int n, float* __restrict__ out)
{
    double sacc = 0.0;
    for (int j = threadIdx.x; j < n; j += 256) sacc += (double)partials[j];
#pragma unroll
    for (int off = 32; off > 0; off >>= 1)
        sacc += __shfl_down(sacc, off, 64);
    __shared__ double ds[4];
    const int lane = threadIdx.x & 63;
    const int wid  = threadIdx.x >> 6;
    if (lane == 0) ds[wid] = sacc;
    __syncthreads();
    if (threadIdx.x == 0) out[0] = (float)(ds[0] + ds[1] + ds[2] + ds[3]);
}

extern "C" void kernel_launch(void* const* d_in, const int* in_sizes, int n_in,
                              void* d_out, int out_size, void* d_ws, size_t ws_size,
                              hipStream_t stream) {
    const float* pred   = (const float*)d_in[0];
    const float* target = (const float*)d_in[1];
    const float* Tarr   = (const float*)d_in[2];
    const float* g      = (const float*)d_in[3];
    const float* dirs   = (const float*)d_in[4];
    const float* noise  = (const float*)d_in[5];
    const int B = in_sizes[2];  // T is (B,)

    float* partials = (float*)d_ws;
    float* out      = (float*)d_out;

    const int block = 256;
    const int grid  = (B + block - 1) / block;
    nrtl_loss_kernel<<<grid, block, 0, stream>>>(pred, target, Tarr, g, dirs, noise, partials, B);
    reduce_kernel<<<1, block, 0, stream>>>(partials, grid, out);
}